// Round 1
// 123.804 us; speedup vs baseline: 1.1187x; 1.1187x over previous
//
#include <hip/hip_runtime.h>

typedef _Float16 f16x8 __attribute__((ext_vector_type(8)));
typedef float f32x4 __attribute__((ext_vector_type(4)));

#define B_  8
#define LQ  2048
#define LC  4096
#define DD  256

// async global->LDS, 16B per lane. LDS dest is wave-uniform base + lane*16.
__device__ __forceinline__ void gload_lds16(const void* g, void* l) {
    __builtin_amdgcn_global_load_lds(
        (const __attribute__((address_space(1))) unsigned int*)g,
        (__attribute__((address_space(3))) unsigned int*)l,
        16, 0, 0);
}

// Convert query only (context is consumed as f32 directly by gemm + out).
__global__ __launch_bounds__(256)
void convert_q(const float* __restrict__ q, _Float16* __restrict__ qf) {
    const int i = (blockIdx.x * 256 + threadIdx.x) * 8;   // 2048 blocks exactly cover 8*2048*256
    const float4 a = *(const float4*)(q + i);
    const float4 c = *(const float4*)(q + i + 4);
    f16x8 o;
    o[0] = (_Float16)a.x; o[1] = (_Float16)a.y; o[2] = (_Float16)a.z; o[3] = (_Float16)a.w;
    o[4] = (_Float16)c.x; o[5] = (_Float16)c.y; o[6] = (_Float16)c.z; o[7] = (_Float16)c.w;
    *(f16x8*)(qf + i) = o;
}

// One block per (b, 128-ctx tile); grid linear so block id % 8 == b -> all 32
// blocks of batch b share one XCD's L2 (qf panel = 1 MB, L2 = 4 MB).
// Pipeline: 72 slots (8 A-chunks f32 interleaved into nt=0, then 60 B-chunks)
// through 4 x 16KB LDS buffers, depth-3 prefetch, counted vmcnt(8) -- never 0
// until the tail. A-chunks: 128 rows x 32 f32 (128 B/row, 8 x 16B groups) --
// identical geometry + XOR swizzle to B-chunks (128 rows x 64 f16).
__global__ __launch_bounds__(256, 1)
void gemm_max_kernel(const _Float16* __restrict__ qf,
                     const float* __restrict__ ctx,
                     float* __restrict__ scores) {
    __shared__ __align__(16) _Float16 Buf[4][8192];   // 4 x 16 KB
    __shared__ float red[2][128];

    const int bid = blockIdx.x;
    const int b   = bid & 7;     // XCD affinity: batch b -> XCD b
    const int mt  = bid >> 3;    // ctx tile 0..31

    const int tid  = threadIdx.x;
    const int lane = tid & 63;
    const int wave = tid >> 6;
    const int wm   = wave >> 1;  // ctx half
    const int wn   = wave & 1;   // query half
    const int quad = lane >> 4;
    const int l15  = lane & 15;

    const float*    Ag = ctx + ((size_t)b * LC + (size_t)mt * 128) * DD;
    const _Float16* Bg = qf  + (size_t)b * LQ * DD;

    // staging: thread t -> row srow (per 32-row pass), LDS group g_store,
    // global group g_glob = g_store ^ (row & 7)  (32 | rows => row&7 == srow&7)
    const int srow    = tid >> 3;
    const int g_store = tid & 7;
    const int g_glob  = g_store ^ (srow & 7);

    // A chunk j: k-range [j*32, j*32+32) as f32; group = 4 floats = 16 B
#define STAGE_A(j, bufi)                                                        \
    {                                                                           \
        _Pragma("unroll")                                                       \
        for (int p = 0; p < 4; ++p)                                             \
            gload_lds16(Ag + (size_t)(p * 32 + srow) * DD + (j) * 32 + g_glob * 4, \
                        (char*)Buf[bufi] + p * 4096 + tid * 16);                \
    }

    // B chunk c (c = nt*4 + kc): query rows [nt*128, +128), k [kc*64, +64) f16
#define STAGE_B(c, bufi)                                                        \
    {                                                                           \
        const _Float16* _s = Bg + (size_t)((c) >> 2) * 128 * DD + ((c) & 3) * 64; \
        _Pragma("unroll")                                                       \
        for (int p = 0; p < 4; ++p)                                             \
            gload_lds16(_s + (size_t)(p * 32 + srow) * DD + g_glob * 8,         \
                        (char*)Buf[bufi] + p * 4096 + tid * 16);                \
    }

    // counted-vmcnt barrier. sched_barrier(0) pins compute/ds_reads on both
    // sides (rule 18: "memory" clobber alone does not order MFMA/ds_read).
#define SYNC(N)                                                                 \
    {                                                                           \
        __builtin_amdgcn_sched_barrier(0);                                      \
        asm volatile("s_waitcnt vmcnt(" #N ")" ::: "memory");                   \
        __builtin_amdgcn_s_barrier();                                           \
        __builtin_amdgcn_sched_barrier(0);                                      \
    }

    f16x8 af[4][8];   // A fragments, resident for full K=256
    f32x4 acc[4][4];

    // read f32 chunk j from LDS, convert -> af[*][j] (same rte cast as before)
#define COMPUTE_A(j, bufi)                                                      \
    {                                                                           \
        _Pragma("unroll")                                                       \
        for (int mi = 0; mi < 4; ++mi) {                                        \
            const int row = wm * 64 + mi * 16 + l15;                            \
            const int p0  = (2 * quad) ^ (row & 7);                             \
            const int p1  = (2 * quad + 1) ^ (row & 7);                         \
            const f32x4 v0 = *(const f32x4*)((const char*)Buf[bufi] + row * 128 + p0 * 16); \
            const f32x4 v1 = *(const f32x4*)((const char*)Buf[bufi] + row * 128 + p1 * 16); \
            f16x8 o;                                                            \
            o[0] = (_Float16)v0[0]; o[1] = (_Float16)v0[1];                     \
            o[2] = (_Float16)v0[2]; o[3] = (_Float16)v0[3];                     \
            o[4] = (_Float16)v1[0]; o[5] = (_Float16)v1[1];                     \
            o[6] = (_Float16)v1[2]; o[7] = (_Float16)v1[3];                     \
            af[mi][j] = o;                                                      \
        }                                                                       \
    }

#define COMPUTE_B(kc, bufi)                                                     \
    {                                                                           \
        _Pragma("unroll")                                                       \
        for (int ksl = 0; ksl < 2; ++ksl) {                                     \
            f16x8 bfv[4];                                                       \
            _Pragma("unroll")                                                   \
            for (int ni = 0; ni < 4; ++ni) {                                    \
                const int row = wn * 64 + ni * 16 + l15;                        \
                const int pos = (ksl * 4 + quad) ^ (row & 7);                   \
                bfv[ni] = *(const f16x8*)((const char*)Buf[bufi] + row * 128 + pos * 16); \
            }                                                                   \
            _Pragma("unroll")                                                   \
            for (int mi = 0; mi < 4; ++mi)                                      \
                _Pragma("unroll")                                               \
                for (int ni = 0; ni < 4; ++ni)                                  \
                    acc[mi][ni] = __builtin_amdgcn_mfma_f32_16x16x32_f16(       \
                        af[mi][(kc) * 2 + ksl], bfv[ni], acc[mi][ni], 0, 0, 0); \
        }                                                                       \
    }

#define ACC_INIT                                                                \
    {                                                                           \
        _Pragma("unroll")                                                       \
        for (int mi = 0; mi < 4; ++mi)                                          \
            _Pragma("unroll")                                                   \
            for (int ni = 0; ni < 4; ++ni) acc[mi][ni] = (f32x4)0.0f;           \
    }

#define ACC_FOLD                                                                \
    {                                                                           \
        _Pragma("unroll")                                                       \
        for (int mi = 0; mi < 4; ++mi)                                          \
            _Pragma("unroll")                                                   \
            for (int r = 0; r < 4; ++r)                                         \
                rm[mi][r] = fmaxf(rm[mi][r],                                    \
                                  fmaxf(fmaxf(acc[mi][0][r], acc[mi][1][r]),    \
                                        fmaxf(acc[mi][2][r], acc[mi][3][r])));  \
    }

    float rm[4][4];
#pragma unroll
    for (int mi = 0; mi < 4; ++mi)
#pragma unroll
        for (int r = 0; r < 4; ++r) rm[mi][r] = -3.4e38f;

    // ---- prologue: slots 0..11 = A0 A1 B0 | A2 A3 B1 | A4 A5 B2 | A6 A7 B3
    // slot s computes buf s&3; stage at s targets slot s+3 -> buf (s+3)&3
    // (= buf last read at s-1, whose reads completed before this barrier).
    // vmcnt ledger: 3 stages (12 loads) in flight; each SYNC(8) retires the
    // oldest 4 (= the chunk about to be read), each stage adds 4.
    STAGE_A(0, 0); STAGE_A(1, 1); STAGE_B(0, 2);
    ACC_INIT;
    SYNC(8);  STAGE_A(2, 3);  COMPUTE_A(0, 0);
    SYNC(8);  STAGE_A(3, 0);  COMPUTE_A(1, 1);
    SYNC(8);  STAGE_B(1, 1);  COMPUTE_B(0, 2);
    SYNC(8);  STAGE_A(4, 2);  COMPUTE_A(2, 3);
    SYNC(8);  STAGE_A(5, 3);  COMPUTE_A(3, 0);
    SYNC(8);  STAGE_B(2, 0);  COMPUTE_B(1, 1);
    SYNC(8);  STAGE_A(6, 1);  COMPUTE_A(4, 2);
    SYNC(8);  STAGE_A(7, 2);  COMPUTE_A(5, 3);
    SYNC(8);  STAGE_B(3, 3);  COMPUTE_B(2, 0);
    SYNC(8);  STAGE_B(4, 0);  COMPUTE_A(6, 1);
    SYNC(8);  STAGE_B(5, 1);  COMPUTE_A(7, 2);
    SYNC(8);  STAGE_B(6, 2);  COMPUTE_B(3, 3);
    ACC_FOLD;                                   // query tile nt=0 done

    // ---- main: nt = 1..15; chunk c = nt*4+kc uses buf kc, stage c+3 -> buf (kc+3)&3
#pragma unroll 1
    for (int nt = 1; nt < 16; ++nt) {
        const int c0 = nt * 4;
        ACC_INIT;
        SYNC(8);
        STAGE_B(c0 + 3, 3);                 // nt=15: chunk 63 (last)
        COMPUTE_B(0, 0);
        SYNC(8);
        if (nt < 15) STAGE_B(c0 + 4, 0);
        COMPUTE_B(1, 1);
        if (nt < 15) { SYNC(8); STAGE_B(c0 + 5, 1); }
        else         { SYNC(4); }           // tail: only chunks 70,71 in flight
        COMPUTE_B(2, 2);
        if (nt < 15) { SYNC(8); STAGE_B(c0 + 6, 2); }
        else         { SYNC(0); }           // drain last chunk
        COMPUTE_B(3, 3);
        ACC_FOLD;
    }

    // ---- epilogue: reduce 16 col lanes, then the two wn halves
#pragma unroll
    for (int sh = 1; sh <= 8; sh <<= 1)
#pragma unroll
        for (int mi = 0; mi < 4; ++mi)
#pragma unroll
            for (int r = 0; r < 4; ++r)
                rm[mi][r] = fmaxf(rm[mi][r], __shfl_xor(rm[mi][r], sh, 64));

    if (l15 == 0) {
#pragma unroll
        for (int mi = 0; mi < 4; ++mi)
#pragma unroll
            for (int r = 0; r < 4; ++r)
                red[wn][wm * 64 + mi * 16 + quad * 4 + r] = rm[mi][r];
    }
    __syncthreads();
    if (tid < 128)
        scores[(size_t)b * LC + mt * 128 + tid] = fmaxf(red[0][tid], red[1][tid]);

#undef STAGE_A
#undef STAGE_B
#undef SYNC
#undef COMPUTE_A
#undef COMPUTE_B
#undef ACC_INIT
#undef ACC_FOLD
}

// Fused softmax-stats + weighted context sum. Each block recomputes M and the
// softmax denominator from the 4096 scores (16 KB, L2-hit, deterministic ->
// identical across blocks), then accumulates its 64-row chunk of
// out[b][d] = sum_c softmax(scores)[c] * ctx[b][c][d]   (ctx read as f32).
__global__ __launch_bounds__(256)
void out_kernel(const float* __restrict__ scores, const float* __restrict__ ctx,
                float* __restrict__ out) {
    const int ch   = blockIdx.x;   // 0..63
    const int b    = blockIdx.y;   // 0..7
    const int tid  = threadIdx.x;
    const int lane = tid & 63;
    const int wave = tid >> 6;
    __shared__ float smax[4];
    __shared__ float ssum[4];
    __shared__ float pl[64];

    const float* sb = scores + (size_t)b * LC;

    float sv[16];
    float lmax = -3.4e38f;
#pragma unroll
    for (int j = 0; j < 16; ++j) {
        sv[j] = sb[tid + j * 256];
        lmax  = fmaxf(lmax, sv[j]);
    }
    for (int sh = 1; sh < 64; sh <<= 1)
        lmax = fmaxf(lmax, __shfl_xor(lmax, sh, 64));
    if (lane == 0) smax[wave] = lmax;
    __syncthreads();
    const float M = fmaxf(fmaxf(smax[0], smax[1]), fmaxf(smax[2], smax[3]));

    float lsum = 0.f;
#pragma unroll
    for (int j = 0; j < 16; ++j)
        lsum += expf(sv[j] - M);
    for (int sh = 1; sh < 64; sh <<= 1)
        lsum += __shfl_xor(lsum, sh, 64);
    if (lane == 0) ssum[wave] = lsum;
    __syncthreads();
    const float inv = 1.f / (ssum[0] + ssum[1] + ssum[2] + ssum[3]);

    if (tid < 64) pl[tid] = expf(sb[ch * 64 + tid] - M) * inv;
    __syncthreads();

    const float* cb = ctx + ((size_t)b * LC + (size_t)ch * 64) * DD;
    float acc = 0.f;
#pragma unroll 8
    for (int i = 0; i < 64; ++i)
        acc += pl[i] * cb[(size_t)i * DD + tid];   // coalesced f32
    atomicAdd(&out[b * DD + tid], acc);
}

extern "C" void kernel_launch(void* const* d_in, const int* in_sizes, int n_in,
                              void* d_out, int out_size, void* d_ws, size_t ws_size,
                              hipStream_t stream) {
    const float* q   = (const float*)d_in[0];   // [8, 2048, 256] f32
    const float* ctx = (const float*)d_in[1];   // [8, 4096, 256] f32
    float* out = (float*)d_out;                 // [8, 1, 256] f32

    // ws layout (bytes):
    //   qf     @ 0        : 8*2048*256*2 = 8,388,608
    //   scores @ 8388608  : 8*4096*4     =   131,072
    char* ws = (char*)d_ws;
    _Float16* qf  = (_Float16*)(ws);
    float* scores = (float*)(ws + 8388608);

    hipMemsetAsync(d_out, 0, (size_t)out_size * sizeof(float), stream);
    convert_q<<<2048, 256, 0, stream>>>(q, qf);
    gemm_max_kernel<<<256, 256, 0, stream>>>(qf, ctx, scores);
    out_kernel<<<dim3(64, 8), 256, 0, stream>>>(scores, ctx, out);
}

// Round 2
// 122.050 us; speedup vs baseline: 1.1348x; 1.0144x over previous
//
#include <hip/hip_runtime.h>

typedef _Float16 f16x8 __attribute__((ext_vector_type(8)));
typedef float f32x4 __attribute__((ext_vector_type(4)));

#define B_  8
#define LQ  2048
#define LC  4096
#define DD  256

// async global->LDS, 16B per lane. LDS dest is wave-uniform base + lane*16.
__device__ __forceinline__ void gload_lds16(const void* g, void* l) {
    __builtin_amdgcn_global_load_lds(
        (const __attribute__((address_space(1))) unsigned int*)g,
        (__attribute__((address_space(3))) unsigned int*)l,
        16, 0, 0);
}

// Convert query only (context is consumed as f32 directly by gemm + out).
// Also zeroes `out` (replaces the hipMemsetAsync dispatch; out_kernel's
// atomicAdds run two kernels later in stream order).
__global__ __launch_bounds__(256)
void convert_q(const float* __restrict__ q, _Float16* __restrict__ qf,
               float* __restrict__ out) {
    if (blockIdx.x < 8) out[blockIdx.x * 256 + threadIdx.x] = 0.f;
    const int i = (blockIdx.x * 256 + threadIdx.x) * 8;   // 2048 blocks cover 8*2048*256
    const float4 a = *(const float4*)(q + i);
    const float4 c = *(const float4*)(q + i + 4);
    f16x8 o;
    o[0] = (_Float16)a.x; o[1] = (_Float16)a.y; o[2] = (_Float16)a.z; o[3] = (_Float16)a.w;
    o[4] = (_Float16)c.x; o[5] = (_Float16)c.y; o[6] = (_Float16)c.z; o[7] = (_Float16)c.w;
    *(f16x8*)(qf + i) = o;
}

// One block per (b, 128-ctx tile); bid&7 = b -> batch b's 32 blocks share one
// XCD's L2 (qf panel = 1 MB). 512 threads = 8 waves = 2 waves/SIMD: wave-level
// TLP hides ds_read latency + MFMA issue bubbles (1 wave/SIMD in round 1 left
// MfmaUtil at 29%). Wave grid 2(ctx)x4(query): mi=4, ni=2 keeps B-fragment
// LDS reads at 2048/block (a 4x2 grid would double them past the MFMA floor).
// Pipeline: 72 slots (8 A f32 chunks interleaved into nt=0, then 60 B chunks)
// through 4 x 16KB buffers, depth-3 prefetch, counted vmcnt(4) -- 2 loads per
// thread per stage -- never 0 until the tail.
__global__ __launch_bounds__(512, 2)
void gemm_max_kernel(const _Float16* __restrict__ qf,
                     const float* __restrict__ ctx,
                     float* __restrict__ scores) {
    __shared__ __align__(16) _Float16 Buf[4][8192];   // 4 x 16 KB
    __shared__ float red[4][128];

    const int bid = blockIdx.x;
    const int b   = bid & 7;     // XCD affinity: batch b -> XCD b
    const int mt  = bid >> 3;    // ctx tile 0..31

    const int tid  = threadIdx.x;
    const int lane = tid & 63;
    const int wave = tid >> 6;   // 0..7
    const int wm   = wave >> 2;  // ctx half   (0..1) -> 64 rows each
    const int wn   = wave & 3;   // query slot (0..3) -> 32 cols each
    const int quad = lane >> 4;
    const int l15  = lane & 15;

    const float*    Ag = ctx + ((size_t)b * LC + (size_t)mt * 128) * DD;
    const _Float16* Bg = qf  + (size_t)b * LQ * DD;

    // staging: 512 threads x 16 B x 2 passes = 16 KB chunk.
    // thread t -> row srow (per 64-row pass), LDS group g_store, global group
    // g_glob = g_store ^ (row & 7)   (64 | pass stride => row&7 == srow&7)
    const int srow    = tid >> 3;    // 0..63
    const int g_store = tid & 7;
    const int g_glob  = g_store ^ (srow & 7);

    // A chunk j: k-range [j*32, j*32+32) as f32; group = 4 floats = 16 B
#define STAGE_A(j, bufi)                                                        \
    {                                                                           \
        _Pragma("unroll")                                                       \
        for (int p = 0; p < 2; ++p)                                             \
            gload_lds16(Ag + (size_t)(p * 64 + srow) * DD + (j) * 32 + g_glob * 4, \
                        (char*)Buf[bufi] + p * 8192 + tid * 16);                \
    }

    // B chunk c (c = nt*4 + kc): query rows [nt*128, +128), k [kc*64, +64) f16
#define STAGE_B(c, bufi)                                                        \
    {                                                                           \
        const _Float16* _s = Bg + (size_t)((c) >> 2) * 128 * DD + ((c) & 3) * 64; \
        _Pragma("unroll")                                                       \
        for (int p = 0; p < 2; ++p)                                             \
            gload_lds16(_s + (size_t)(p * 64 + srow) * DD + g_glob * 8,         \
                        (char*)Buf[bufi] + p * 8192 + tid * 16);                \
    }

    // counted-vmcnt barrier. sched_barrier(0) pins compute/ds_reads on both
    // sides (rule 18: "memory" clobber alone does not order MFMA/ds_read).
#define SYNC(N)                                                                 \
    {                                                                           \
        __builtin_amdgcn_sched_barrier(0);                                      \
        asm volatile("s_waitcnt vmcnt(" #N ")" ::: "memory");                   \
        __builtin_amdgcn_s_barrier();                                           \
        __builtin_amdgcn_sched_barrier(0);                                      \
    }

    f16x8 af[4][8];   // A fragments, resident for full K=256
    f32x4 acc[4][2];

    // read f32 chunk j from LDS, convert -> af[*][j]
#define COMPUTE_A(j, bufi)                                                      \
    {                                                                           \
        _Pragma("unroll")                                                       \
        for (int mi = 0; mi < 4; ++mi) {                                        \
            const int row = wm * 64 + mi * 16 + l15;                            \
            const int p0  = (2 * quad) ^ (row & 7);                             \
            const int p1  = (2 * quad + 1) ^ (row & 7);                         \
            const f32x4 v0 = *(const f32x4*)((const char*)Buf[bufi] + row * 128 + p0 * 16); \
            const f32x4 v1 = *(const f32x4*)((const char*)Buf[bufi] + row * 128 + p1 * 16); \
            f16x8 o;                                                            \
            o[0] = (_Float16)v0[0]; o[1] = (_Float16)v0[1];                     \
            o[2] = (_Float16)v0[2]; o[3] = (_Float16)v0[3];                     \
            o[4] = (_Float16)v1[0]; o[5] = (_Float16)v1[1];                     \
            o[6] = (_Float16)v1[2]; o[7] = (_Float16)v1[3];                     \
            af[mi][j] = o;                                                      \
        }                                                                       \
    }

#define COMPUTE_B(kc, bufi)                                                     \
    {                                                                           \
        _Pragma("unroll")                                                       \
        for (int ksl = 0; ksl < 2; ++ksl) {                                     \
            f16x8 bfv[2];                                                       \
            _Pragma("unroll")                                                   \
            for (int ni = 0; ni < 2; ++ni) {                                    \
                const int row = wn * 32 + ni * 16 + l15;                        \
                const int pos = (ksl * 4 + quad) ^ (row & 7);                   \
                bfv[ni] = *(const f16x8*)((const char*)Buf[bufi] + row * 128 + pos * 16); \
            }                                                                   \
            __builtin_amdgcn_s_setprio(1);                                      \
            _Pragma("unroll")                                                   \
            for (int mi = 0; mi < 4; ++mi)                                      \
                _Pragma("unroll")                                               \
                for (int ni = 0; ni < 2; ++ni)                                  \
                    acc[mi][ni] = __builtin_amdgcn_mfma_f32_16x16x32_f16(       \
                        af[mi][(kc) * 2 + ksl], bfv[ni], acc[mi][ni], 0, 0, 0); \
            __builtin_amdgcn_s_setprio(0);                                      \
        }                                                                       \
    }

#define ACC_INIT                                                                \
    {                                                                           \
        _Pragma("unroll")                                                       \
        for (int mi = 0; mi < 4; ++mi)                                          \
            _Pragma("unroll")                                                   \
            for (int ni = 0; ni < 2; ++ni) acc[mi][ni] = (f32x4)0.0f;           \
    }

#define ACC_FOLD                                                                \
    {                                                                           \
        _Pragma("unroll")                                                       \
        for (int mi = 0; mi < 4; ++mi)                                          \
            _Pragma("unroll")                                                   \
            for (int r = 0; r < 4; ++r)                                         \
                rm[mi][r] = fmaxf(rm[mi][r],                                    \
                                  fmaxf(acc[mi][0][r], acc[mi][1][r]));         \
    }

    float rm[4][4];
#pragma unroll
    for (int mi = 0; mi < 4; ++mi)
#pragma unroll
        for (int r = 0; r < 4; ++r) rm[mi][r] = -3.4e38f;

    // ---- prologue: slots 0..11 = A0 A1 B0 | A2 A3 B1 | A4 A5 B2 | A6 A7 B3
    // slot s computes buf s&3; stage at s targets buf (s+3)&3 (last read at
    // slot s-1, reads completed before this slot's barrier).
    // vmcnt ledger: 3 stages (6 loads/thread) in flight; each SYNC(4) retires
    // the oldest 2 (= the chunk about to be read), each stage adds 2.
    STAGE_A(0, 0); STAGE_A(1, 1); STAGE_B(0, 2);
    ACC_INIT;
    SYNC(4);  STAGE_A(2, 3);  COMPUTE_A(0, 0);
    SYNC(4);  STAGE_A(3, 0);  COMPUTE_A(1, 1);
    SYNC(4);  STAGE_B(1, 1);  COMPUTE_B(0, 2);
    SYNC(4);  STAGE_A(4, 2);  COMPUTE_A(2, 3);
    SYNC(4);  STAGE_A(5, 3);  COMPUTE_A(3, 0);
    SYNC(4);  STAGE_B(2, 0);  COMPUTE_B(1, 1);
    SYNC(4);  STAGE_A(6, 1);  COMPUTE_A(4, 2);
    SYNC(4);  STAGE_A(7, 2);  COMPUTE_A(5, 3);
    SYNC(4);  STAGE_B(3, 3);  COMPUTE_B(2, 0);
    SYNC(4);  STAGE_B(4, 0);  COMPUTE_A(6, 1);
    SYNC(4);  STAGE_B(5, 1);  COMPUTE_A(7, 2);
    SYNC(4);  STAGE_B(6, 2);  COMPUTE_B(3, 3);
    ACC_FOLD;                                   // query tile nt=0 done

    // ---- main: nt = 1..15; chunk c = nt*4+kc uses buf kc, stage c+3 -> buf (kc+3)&3
#pragma unroll 1
    for (int nt = 1; nt < 16; ++nt) {
        const int c0 = nt * 4;
        ACC_INIT;
        SYNC(4);
        STAGE_B(c0 + 3, 3);                 // nt=15: chunk 63 (last)
        COMPUTE_B(0, 0);
        SYNC(4);
        if (nt < 15) STAGE_B(c0 + 4, 0);
        COMPUTE_B(1, 1);
        if (nt < 15) { SYNC(4); STAGE_B(c0 + 5, 1); }
        else         { SYNC(2); }           // tail: only chunks 62,63 in flight
        COMPUTE_B(2, 2);
        if (nt < 15) { SYNC(4); STAGE_B(c0 + 6, 2); }
        else         { SYNC(0); }           // drain last chunk
        COMPUTE_B(3, 3);
        ACC_FOLD;
    }

    // ---- epilogue: reduce 16 col lanes, then the four wn slots
#pragma unroll
    for (int sh = 1; sh <= 8; sh <<= 1)
#pragma unroll
        for (int mi = 0; mi < 4; ++mi)
#pragma unroll
            for (int r = 0; r < 4; ++r)
                rm[mi][r] = fmaxf(rm[mi][r], __shfl_xor(rm[mi][r], sh, 64));

    if (l15 == 0) {
#pragma unroll
        for (int mi = 0; mi < 4; ++mi)
#pragma unroll
            for (int r = 0; r < 4; ++r)
                red[wn][wm * 64 + mi * 16 + quad * 4 + r] = rm[mi][r];
    }
    __syncthreads();
    if (tid < 128)
        scores[(size_t)b * LC + mt * 128 + tid] =
            fmaxf(fmaxf(red[0][tid], red[1][tid]),
                  fmaxf(red[2][tid], red[3][tid]));

#undef STAGE_A
#undef STAGE_B
#undef SYNC
#undef COMPUTE_A
#undef COMPUTE_B
#undef ACC_INIT
#undef ACC_FOLD
}

// Fused softmax-stats + weighted context sum. Each block recomputes M and the
// softmax denominator from the 4096 scores (16 KB, L2-hit, deterministic ->
// identical across blocks), then accumulates its 64-row chunk of
// out[b][d] = sum_c softmax(scores)[c] * ctx[b][c][d]   (ctx read as f32).
__global__ __launch_bounds__(256)
void out_kernel(const float* __restrict__ scores, const float* __restrict__ ctx,
                float* __restrict__ out) {
    const int ch   = blockIdx.x;   // 0..63
    const int b    = blockIdx.y;   // 0..7
    const int tid  = threadIdx.x;
    const int lane = tid & 63;
    const int wave = tid >> 6;
    __shared__ float smax[4];
    __shared__ float ssum[4];
    __shared__ float pl[64];

    const float* sb = scores + (size_t)b * LC;

    float sv[16];
    float lmax = -3.4e38f;
#pragma unroll
    for (int j = 0; j < 16; ++j) {
        sv[j] = sb[tid + j * 256];
        lmax  = fmaxf(lmax, sv[j]);
    }
    for (int sh = 1; sh < 64; sh <<= 1)
        lmax = fmaxf(lmax, __shfl_xor(lmax, sh, 64));
    if (lane == 0) smax[wave] = lmax;
    __syncthreads();
    const float M = fmaxf(fmaxf(smax[0], smax[1]), fmaxf(smax[2], smax[3]));

    float lsum = 0.f;
#pragma unroll
    for (int j = 0; j < 16; ++j)
        lsum += expf(sv[j] - M);
    for (int sh = 1; sh < 64; sh <<= 1)
        lsum += __shfl_xor(lsum, sh, 64);
    if (lane == 0) ssum[wave] = lsum;
    __syncthreads();
    const float inv = 1.f / (ssum[0] + ssum[1] + ssum[2] + ssum[3]);

    if (tid < 64) pl[tid] = expf(sb[ch * 64 + tid] - M) * inv;
    __syncthreads();

    const float* cb = ctx + ((size_t)b * LC + (size_t)ch * 64) * DD;
    float acc = 0.f;
#pragma unroll 8
    for (int i = 0; i < 64; ++i)
        acc += pl[i] * cb[(size_t)i * DD + tid];   // coalesced f32
    atomicAdd(&out[b * DD + tid], acc);
}

extern "C" void kernel_launch(void* const* d_in, const int* in_sizes, int n_in,
                              void* d_out, int out_size, void* d_ws, size_t ws_size,
                              hipStream_t stream) {
    const float* q   = (const float*)d_in[0];   // [8, 2048, 256] f32
    const float* ctx = (const float*)d_in[1];   // [8, 4096, 256] f32
    float* out = (float*)d_out;                 // [8, 1, 256] f32

    // ws layout (bytes):
    //   qf     @ 0        : 8*2048*256*2 = 8,388,608
    //   scores @ 8388608  : 8*4096*4     =   131,072
    char* ws = (char*)d_ws;
    _Float16* qf  = (_Float16*)(ws);
    float* scores = (float*)(ws + 8388608);

    convert_q<<<2048, 256, 0, stream>>>(q, qf, out);
    gemm_max_kernel<<<256, 512, 0, stream>>>(qf, ctx, scores);
    out_kernel<<<dim3(64, 8), 256, 0, stream>>>(scores, ctx, out);
}